// Round 8
// baseline (702.617 us; speedup 1.0000x reference)
//
#include <hip/hip_runtime.h>
#include <hip/hip_bf16.h>

#define IN_DIM 128
#define HID    64
#define OUTD   64
#define NPART  8
#define NSUB   64            // windows per partition; 512 blocks total
#define MAXW   200           // max dst-window nodes (ceil(12500/64)=196)
#define BKT_BLOCKS 1600      // k_bcount / k_bwrite grid; NW = BKT_BLOCKS*4 waves

typedef __attribute__((ext_vector_type(8))) short bf16x8;
typedef __attribute__((ext_vector_type(4))) float f32x4;

__device__ __forceinline__ float gelu_exact(float v) {
    return v * 0.5f * (1.0f + erff(v * 0.70710678118654752f));
}
__device__ __forceinline__ short f2bf(float f) {
    __hip_bfloat16 b = __float2bfloat16(f);   // RNE
    return *reinterpret_cast<short*>(&b);
}
__device__ __forceinline__ float bf2f(ushort u) {
    return __uint_as_float(((unsigned)u) << 16);
}

// ---------------------------------------------------------------------------
// K1: node projection via MFMA bf16 (unchanged; ~25us).
// ---------------------------------------------------------------------------
__global__ __launch_bounds__(256) void gat_node_proj_mfma(
    const float* __restrict__ x, const float* __restrict__ w_in,
    const float* __restrict__ b_in, const float* __restrict__ w,
    const float* __restrict__ a,
    ushort* __restrict__ zb, float* __restrict__ s1, float* __restrict__ s2,
    int n_nodes, int ntiles)
{
    __shared__ ushort h0s[4][16 * 64];

    const int tid = threadIdx.x;
    const int wv = tid >> 6, l = tid & 63;
    const int c = l & 15, g = l >> 4;

    bf16x8 B1[4][4];
    #pragma unroll
    for (int s = 0; s < 4; ++s)
        #pragma unroll
        for (int t = 0; t < 4; ++t) {
            bf16x8 f;
            #pragma unroll
            for (int e = 0; e < 8; ++e)
                f[e] = f2bf(w_in[(s * 32 + g * 8 + e) * HID + t * 16 + c]);
            B1[s][t] = f;
        }
    bf16x8 B2[2][4];
    #pragma unroll
    for (int s = 0; s < 2; ++s)
        #pragma unroll
        for (int t = 0; t < 4; ++t) {
            bf16x8 f;
            #pragma unroll
            for (int e = 0; e < 8; ++e)
                f[e] = f2bf(w[(s * 32 + g * 8 + e) * OUTD + t * 16 + c]);
            B2[s][t] = f;
        }
    float bias[4], a1c[4], a2c[4];
    #pragma unroll
    for (int t = 0; t < 4; ++t) {
        bias[t] = b_in[t * 16 + c];
        a1c[t]  = a[t * 16 + c];
        a2c[t]  = a[OUTD + t * 16 + c];
    }

    ushort* hrow = &h0s[wv][0];

    for (int tile = blockIdx.x; tile < ntiles; tile += gridDim.x) {
        const int nbase = tile * 64 + wv * 16;

        const int row = min(nbase + c, n_nodes - 1);
        const float* xp = x + (size_t)row * IN_DIM;
        bf16x8 A1[4];
        #pragma unroll
        for (int s = 0; s < 4; ++s) {
            const float4 u0 = *(const float4*)(xp + s * 32 + g * 8);
            const float4 u1 = *(const float4*)(xp + s * 32 + g * 8 + 4);
            bf16x8 f;
            f[0] = f2bf(u0.x); f[1] = f2bf(u0.y); f[2] = f2bf(u0.z); f[3] = f2bf(u0.w);
            f[4] = f2bf(u1.x); f[5] = f2bf(u1.y); f[6] = f2bf(u1.z); f[7] = f2bf(u1.w);
            A1[s] = f;
        }

        #pragma unroll
        for (int t = 0; t < 4; ++t) {
            f32x4 acc = {0.f, 0.f, 0.f, 0.f};
            #pragma unroll
            for (int s = 0; s < 4; ++s)
                acc = __builtin_amdgcn_mfma_f32_16x16x32_bf16(A1[s], B1[s][t], acc, 0, 0, 0);
            #pragma unroll
            for (int r = 0; r < 4; ++r) {
                const int m = g * 4 + r;
                const int n = t * 16 + c;
                const float h0 = gelu_exact(acc[r] + bias[t]);
                hrow[m * 64 + (n ^ ((m & 7) << 3))] = (ushort)f2bf(h0);
            }
        }
        __syncthreads();

        bf16x8 A2[2];
        #pragma unroll
        for (int s = 0; s < 2; ++s) {
            const int k = s * 32 + g * 8;
            A2[s] = *(const bf16x8*)(hrow + c * 64 + (k ^ ((c & 7) << 3)));
        }

        f32x4 C2[4];
        #pragma unroll
        for (int t = 0; t < 4; ++t) {
            f32x4 acc = {0.f, 0.f, 0.f, 0.f};
            acc = __builtin_amdgcn_mfma_f32_16x16x32_bf16(A2[0], B2[0][t], acc, 0, 0, 0);
            acc = __builtin_amdgcn_mfma_f32_16x16x32_bf16(A2[1], B2[1][t], acc, 0, 0, 0);
            C2[t] = acc;
        }

        float p1v[4] = {0.f, 0.f, 0.f, 0.f}, p2v[4] = {0.f, 0.f, 0.f, 0.f};
        #pragma unroll
        for (int t = 0; t < 4; ++t)
            #pragma unroll
            for (int r = 0; r < 4; ++r) {
                p1v[r] = fmaf(C2[t][r], a1c[t], p1v[r]);
                p2v[r] = fmaf(C2[t][r], a2c[t], p2v[r]);
                const int node = nbase + g * 4 + r;
                if (node < n_nodes)
                    zb[(size_t)node * OUTD + t * 16 + c] = (ushort)f2bf(C2[t][r]);
            }

        #pragma unroll
        for (int r = 0; r < 4; ++r) {
            p1v[r] += __shfl_xor(p1v[r], 1, 64);
            p1v[r] += __shfl_xor(p1v[r], 2, 64);
            p1v[r] += __shfl_xor(p1v[r], 4, 64);
            p1v[r] += __shfl_xor(p1v[r], 8, 64);
            p2v[r] += __shfl_xor(p2v[r], 1, 64);
            p2v[r] += __shfl_xor(p2v[r], 2, 64);
            p2v[r] += __shfl_xor(p2v[r], 4, 64);
            p2v[r] += __shfl_xor(p2v[r], 8, 64);
        }
        const float v1 = (c == 0) ? p1v[0] : (c == 1) ? p1v[1] : (c == 2) ? p1v[2] : p1v[3];
        const float v2 = (c == 0) ? p2v[0] : (c == 1) ? p2v[1] : (c == 2) ? p2v[2] : p2v[3];
        const int snode = nbase + g * 4 + c;
        if (c < 4 && snode < n_nodes) { s1[snode] = v1; s2[snode] = v2; }
        __syncthreads();
    }
}

// ---------------------------------------------------------------------------
// Deterministic 8-way radix partition (R7, kept: no atomics anywhere).
// Pack: (dst_local<<17)|src needs n_nodes<=131072, part_sz<=16384.
// ---------------------------------------------------------------------------
__global__ __launch_bounds__(256) void k_bcount(
    const int* __restrict__ dst, int* __restrict__ wcnt, int n_edges,
    int part_sz)
{
    const int lane = threadIdx.x & 63;
    const int gw = (blockIdx.x * 256 + threadIdx.x) >> 6;
    const int nw = (gridDim.x * 256) >> 6;

    int cnt[NPART];
    #pragma unroll
    for (int p = 0; p < NPART; ++p) cnt[p] = 0;

    const int tiles = (n_edges + 255) >> 8;
    for (int t = gw; t < tiles; t += nw) {
        const int base = (t << 8) + (lane << 2);
        int p0 = -1, p1 = -1, p2 = -1, p3 = -1;
        if (base + 3 < n_edges) {
            const int4 d4 = *(const int4*)(dst + base);
            p0 = d4.x / part_sz; p1 = d4.y / part_sz;
            p2 = d4.z / part_sz; p3 = d4.w / part_sz;
        } else {
            if (base + 0 < n_edges) p0 = dst[base + 0] / part_sz;
            if (base + 1 < n_edges) p1 = dst[base + 1] / part_sz;
            if (base + 2 < n_edges) p2 = dst[base + 2] / part_sz;
            if (base + 3 < n_edges) p3 = dst[base + 3] / part_sz;
        }
        #pragma unroll
        for (int pp = 0; pp < NPART; ++pp) {
            cnt[pp] += __popcll(__ballot(p0 == pp)) + __popcll(__ballot(p1 == pp))
                     + __popcll(__ballot(p2 == pp)) + __popcll(__ballot(p3 == pp));
        }
    }
    if (lane == 0) {
        #pragma unroll
        for (int pp = 0; pp < NPART; ++pp) wcnt[pp * nw + gw] = cnt[pp];
    }
}

__global__ __launch_bounds__(256) void k_wtot(
    const int* __restrict__ wcnt, int* __restrict__ tot8, int nw)
{
    __shared__ int sb[256];
    const int p = blockIdx.x, tid = threadIdx.x;
    int s = 0;
    for (int i = tid; i < nw; i += 256) s += wcnt[p * nw + i];
    sb[tid] = s;
    __syncthreads();
    #pragma unroll
    for (int off = 128; off; off >>= 1) {
        if (tid < off) sb[tid] += sb[tid + off];
        __syncthreads();
    }
    if (tid == 0) tot8[p] = sb[0];
}

__global__ void k_off8g(const int* __restrict__ tot8, int* __restrict__ off8)
{
    if (threadIdx.x == 0) {
        int a = 0;
        for (int p = 0; p < NPART; ++p) { off8[p] = a; a += tot8[p]; }
        off8[NPART] = a;
    }
}

__global__ __launch_bounds__(256) void k_wscan(
    int* __restrict__ wcnt, const int* __restrict__ off8, int nw)
{
    __shared__ int buf[256];
    const int p = blockIdx.x, tid = threadIdx.x;
    int running = off8[p];
    for (int c0 = 0; c0 < nw; c0 += 256) {
        const int i = c0 + tid;
        const int v = (i < nw) ? wcnt[p * nw + i] : 0;
        buf[tid] = v;
        __syncthreads();
        #pragma unroll
        for (int off = 1; off < 256; off <<= 1) {
            int t = (tid >= off) ? buf[tid - off] : 0;
            __syncthreads();
            buf[tid] += t;
            __syncthreads();
        }
        if (i < nw) wcnt[p * nw + i] = running + buf[tid] - v;
        running += buf[255];
        __syncthreads();
    }
}

__global__ __launch_bounds__(256) void k_bwrite(
    const int* __restrict__ src, const int* __restrict__ dst,
    const int* __restrict__ wbase, unsigned* __restrict__ bkt,
    int n_edges, int part_sz)
{
    const int lane = threadIdx.x & 63;
    const int gw = (blockIdx.x * 256 + threadIdx.x) >> 6;
    const int nw = (gridDim.x * 256) >> 6;
    const unsigned long long below = (lane == 63) ? 0x7FFFFFFFFFFFFFFFull
                                                  : ((1ull << lane) - 1ull);

    int base8[NPART];
    #pragma unroll
    for (int pp = 0; pp < NPART; ++pp) base8[pp] = wbase[pp * nw + gw];

    const int tiles = (n_edges + 255) >> 8;
    for (int t = gw; t < tiles; t += nw) {
        const int base = (t << 8) + (lane << 2);
        int p[4]; unsigned pk[4];
        if (base + 3 < n_edges) {
            const int4 d4 = *(const int4*)(dst + base);
            const int4 s4 = *(const int4*)(src + base);
            p[0] = d4.x / part_sz; pk[0] = ((unsigned)(d4.x - p[0] * part_sz) << 17) | (unsigned)s4.x;
            p[1] = d4.y / part_sz; pk[1] = ((unsigned)(d4.y - p[1] * part_sz) << 17) | (unsigned)s4.y;
            p[2] = d4.z / part_sz; pk[2] = ((unsigned)(d4.z - p[2] * part_sz) << 17) | (unsigned)s4.z;
            p[3] = d4.w / part_sz; pk[3] = ((unsigned)(d4.w - p[3] * part_sz) << 17) | (unsigned)s4.w;
        } else {
            #pragma unroll
            for (int j = 0; j < 4; ++j) {
                if (base + j < n_edges) {
                    const int d = dst[base + j];
                    p[j] = d / part_sz;
                    pk[j] = ((unsigned)(d - p[j] * part_sz) << 17) | (unsigned)src[base + j];
                } else p[j] = -1;
            }
        }
        #pragma unroll
        for (int pp = 0; pp < NPART; ++pp) {
            const unsigned long long m0 = __ballot(p[0] == pp);
            const unsigned long long m1 = __ballot(p[1] == pp);
            const unsigned long long m2 = __ballot(p[2] == pp);
            const unsigned long long m3 = __ballot(p[3] == pp);
            const int k0 = __popcll(m0), k1 = __popcll(m1);
            const int k2 = __popcll(m2), k3 = __popcll(m3);
            const int go = base8[pp];
            if ((m0 >> lane) & 1) bkt[go + __popcll(m0 & below)] = pk[0];
            if ((m1 >> lane) & 1) bkt[go + k0 + __popcll(m1 & below)] = pk[1];
            if ((m2 >> lane) & 1) bkt[go + k0 + k1 + __popcll(m2 & below)] = pk[2];
            if ((m3 >> lane) & 1) bkt[go + k0 + k1 + k2 + __popcll(m3 & below)] = pk[3];
            base8[pp] = go + k0 + k1 + k2 + k3;
        }
    }
}

// ---------------------------------------------------------------------------
// FUSED aggregation: replaces hist/deg-scan/scatter/agg entirely.
// Block b: partition p=b&7 (XCD-affine with the bucket's writers/readers),
// dst window [wlo, wlo+wn) of <=MAXW nodes; LDS accumulator acc[wn][64]+den.
// Scans partition bucket (L2-resident), ballot-filters window edges (~4 per
// wave-tile), extracts via wave-uniform mask iteration, batches 4 row-gathers
// for MLP, accumulates with ds_add_f32 (bank-conflict-free: bank=lane%32).
// ---------------------------------------------------------------------------
__global__ __launch_bounds__(512) void k_fused_agg(
    const unsigned* __restrict__ bkt, const int* __restrict__ tot8,
    const int* __restrict__ off8,
    const float* __restrict__ s1, const float* __restrict__ s2,
    const ushort* __restrict__ zb, float* __restrict__ h,
    int n_nodes, int part_sz)
{
    __shared__ float accs[MAXW * 64];   // 51.2 KB
    __shared__ float dens[MAXW];

    const int p = blockIdx.x & (NPART - 1);
    const int sub = blockIdx.x >> 3;
    const int pbase = p * part_sz;
    const int psz = min(part_sz, n_nodes - pbase);
    const int wsz = (part_sz + NSUB - 1) / NSUB;    // 196 for n=100000
    const int wlo = sub * wsz;
    const int wn = min(wsz, psz - wlo);
    if (wn <= 0) return;

    const int tid = threadIdx.x;
    const int lane = tid & 63;

    for (int i = tid; i < wn * 64; i += 512) accs[i] = 0.f;
    for (int i = tid; i < wn; i += 512) dens[i] = 0.f;
    __syncthreads();

    const int nB = tot8[p];
    const unsigned* bucket = bkt + off8[p];
    const int whi = wlo + wn;

    for (int tb = 0; tb < nB; tb += 2048) {
        // 4 coalesced slices of 512 edges each
        const int i0 = tb + tid, i1 = i0 + 512, i2 = i1 + 512, i3 = i2 + 512;
        const unsigned pk0 = (i0 < nB) ? bucket[i0] : 0u;
        const unsigned pk1 = (i1 < nB) ? bucket[i1] : 0u;
        const unsigned pk2 = (i2 < nB) ? bucket[i2] : 0u;
        const unsigned pk3 = (i3 < nB) ? bucket[i3] : 0u;
        const int dl0 = (int)(pk0 >> 17), sv0 = (int)(pk0 & 0x1FFFFu);
        const int dl1 = (int)(pk1 >> 17), sv1 = (int)(pk1 & 0x1FFFFu);
        const int dl2 = (int)(pk2 >> 17), sv2 = (int)(pk2 & 0x1FFFFu);
        const int dl3 = (int)(pk3 >> 17), sv3 = (int)(pk3 & 0x1FFFFu);

        unsigned long long m0 = __ballot((i0 < nB) && dl0 >= wlo && dl0 < whi);
        unsigned long long m1 = __ballot((i1 < nB) && dl1 >= wlo && dl1 < whi);
        unsigned long long m2 = __ballot((i2 < nB) && dl2 >= wlo && dl2 < whi);
        unsigned long long m3 = __ballot((i3 < nB) && dl3 >= wlo && dl3 < whi);

#define TAKE(S, D) \
        if (m0) { const int b_ = __builtin_ctzll(m0); m0 &= m0 - 1; \
                  S = __shfl(sv0, b_, 64); D = __shfl(dl0, b_, 64); } \
        else if (m1) { const int b_ = __builtin_ctzll(m1); m1 &= m1 - 1; \
                  S = __shfl(sv1, b_, 64); D = __shfl(dl1, b_, 64); } \
        else if (m2) { const int b_ = __builtin_ctzll(m2); m2 &= m2 - 1; \
                  S = __shfl(sv2, b_, 64); D = __shfl(dl2, b_, 64); } \
        else if (m3) { const int b_ = __builtin_ctzll(m3); m3 &= m3 - 1; \
                  S = __shfl(sv3, b_, 64); D = __shfl(dl3, b_, 64); } \
        else { S = -1; D = wlo; }

        while (m0 | m1 | m2 | m3) {
            int a0, d0_, a1, d1_, a2, d2_, a3, d3_;
            TAKE(a0, d0_) TAKE(a1, d1_) TAKE(a2, d2_) TAKE(a3, d3_)
            const int c0 = max(a0, 0), c1 = max(a1, 0);
            const int c2 = max(a2, 0), c3 = max(a3, 0);
            // uniform-address loads (broadcast, 1 line each; L2-warm)
            const float e0 = s1[c0] + s2[pbase + d0_];
            const float e1 = s1[c1] + s2[pbase + d1_];
            const float e2 = s1[c2] + s2[pbase + d2_];
            const float e3 = s1[c3] + s2[pbase + d3_];
            const float q0 = (a0 >= 0) ? __expf(e0 > 0.f ? e0 : 0.01f * e0) : 0.f;
            const float q1 = (a1 >= 0) ? __expf(e1 > 0.f ? e1 : 0.01f * e1) : 0.f;
            const float q2 = (a2 >= 0) ? __expf(e2 > 0.f ? e2 : 0.01f * e2) : 0.f;
            const float q3 = (a3 >= 0) ? __expf(e3 > 0.f ? e3 : 0.01f * e3) : 0.f;
            // 4 independent row gathers in flight
            const float z0 = bf2f(zb[(size_t)c0 * OUTD + lane]);
            const float z1 = bf2f(zb[(size_t)c1 * OUTD + lane]);
            const float z2 = bf2f(zb[(size_t)c2 * OUTD + lane]);
            const float z3 = bf2f(zb[(size_t)c3 * OUTD + lane]);
            if (a0 >= 0) atomicAdd(&accs[(d0_ - wlo) * 64 + lane], q0 * z0);
            if (a1 >= 0) atomicAdd(&accs[(d1_ - wlo) * 64 + lane], q1 * z1);
            if (a2 >= 0) atomicAdd(&accs[(d2_ - wlo) * 64 + lane], q2 * z2);
            if (a3 >= 0) atomicAdd(&accs[(d3_ - wlo) * 64 + lane], q3 * z3);
            if (lane == 0) {
                if (a0 >= 0) atomicAdd(&dens[d0_ - wlo], q0);
                if (a1 >= 0) atomicAdd(&dens[d1_ - wlo], q1);
                if (a2 >= 0) atomicAdd(&dens[d2_ - wlo], q2);
                if (a3 >= 0) atomicAdd(&dens[d3_ - wlo], q3);
            }
        }
#undef TAKE
    }
    __syncthreads();

    // normalize + coalesced write
    for (int i = tid; i < wn * 64; i += 512) {
        const int nl = i >> 6;
        h[(size_t)(pbase + wlo + nl) * OUTD + (i & 63)] =
            accs[i] / fmaxf(dens[nl], 1e-9f);
    }
}

extern "C" void kernel_launch(void* const* d_in, const int* in_sizes, int n_in,
                              void* d_out, int out_size, void* d_ws, size_t ws_size,
                              hipStream_t stream)
{
    const float* x    = (const float*)d_in[0];
    const float* w_in = (const float*)d_in[1];
    const float* b_in = (const float*)d_in[2];
    const float* w    = (const float*)d_in[3];
    const float* a    = (const float*)d_in[4];
    const int*   src  = (const int*)d_in[5];
    const int*   dst  = (const int*)d_in[6];
    const int n_nodes = in_sizes[0] / IN_DIM;
    const int n_edges = in_sizes[5];

    float* h = (float*)d_out;

    const int NW = BKT_BLOCKS * 4;   // waves in bucket kernels

    // workspace (~20.5 MB): zb | s1 | s2 | tot8/off8 pad | wcnt | bkt
    ushort*   zb   = (ushort*)d_ws;                      // n_nodes*64 bf16
    float*    s1   = (float*)(zb + (size_t)n_nodes * OUTD);
    float*    s2   = s1 + n_nodes;
    int*      tot8 = (int*)(s2 + n_nodes);               // 8
    int*      off8 = tot8 + NPART;                       // 9 (region padded to 64)
    int*      wcnt = tot8 + 64;                          // 8*NW
    unsigned* bkt  = (unsigned*)(wcnt + NPART * NW);     // n_edges

    const int ntiles = (n_nodes + 63) / 64;
    const int part_sz = (n_nodes + NPART - 1) / NPART;

    gat_node_proj_mfma<<<523, 256, 0, stream>>>(x, w_in, b_in, w, a,
                                                zb, s1, s2, n_nodes, ntiles);

    k_bcount<<<BKT_BLOCKS, 256, 0, stream>>>(dst, wcnt, n_edges, part_sz);
    k_wtot<<<NPART, 256, 0, stream>>>(wcnt, tot8, NW);
    k_off8g<<<1, 64, 0, stream>>>(tot8, off8);
    k_wscan<<<NPART, 256, 0, stream>>>(wcnt, off8, NW);
    k_bwrite<<<BKT_BLOCKS, 256, 0, stream>>>(src, dst, wcnt, bkt, n_edges, part_sz);

    k_fused_agg<<<NPART * NSUB, 512, 0, stream>>>(bkt, tot8, off8, s1, s2, zb,
                                                  h, n_nodes, part_sz);
}